// Round 4
// baseline (419.843 us; speedup 1.0000x reference)
//
#include <hip/hip_runtime.h>

#define HID 256
#define NFEAT 9
#define VOCAB 119
#define NLAYERS 4
#define NGRAPHS 256
#define BN_EPS 1e-5f

typedef short short8 __attribute__((ext_vector_type(8)));
typedef float floatx4 __attribute__((ext_vector_type(4)));

__device__ inline unsigned short f2bf(float f) {
    unsigned int u = __float_as_uint(f);
    unsigned int r = u + 0x7FFF + ((u >> 16) & 1);  // RNE
    return (unsigned short)(r >> 16);
}
__device__ inline float bf2f(unsigned short u) {
    return __uint_as_float(((unsigned int)u) << 16);
}

// ---------------- degree count (in-degree over dst) ----------------
__global__ void deg_kernel(const int* __restrict__ dst, int* __restrict__ degi, int E) {
    int i = blockIdx.x * blockDim.x + threadIdx.x;
    if (i < E) atomicAdd(&degi[dst[i]], 1);
}

__global__ void nrm_kernel(const int* __restrict__ degi, float* __restrict__ nrm, int N) {
    int i = blockIdx.x * blockDim.x + threadIdx.x;
    if (i < N) nrm[i] = rsqrtf(1.0f + (float)degi[i]);
}

// ---------------- parallel exclusive scan (single block, 1024 thr) ----------------
__global__ __launch_bounds__(1024) void scan_kernel(const int* __restrict__ degi,
                                                    int* __restrict__ row_ptr, int N) {
    int tid = threadIdx.x;
    int ch = (N + 1023) >> 10;
    int i0 = tid * ch;
    int i1 = min(i0 + ch, N);
    if (i0 > N) i0 = N;
    int local = 0;
    for (int i = i0; i < i1; ++i) local += degi[i];
    int lane = tid & 63, wid = tid >> 6;
    int v = local;
#pragma unroll
    for (int off = 1; off < 64; off <<= 1) {
        int u = __shfl_up(v, off);
        if (lane >= off) v += u;
    }
    __shared__ int wsum[16];
    if (lane == 63) wsum[wid] = v;
    __syncthreads();
    if (tid < 16) {
        int w = wsum[tid];
#pragma unroll
        for (int off = 1; off < 16; off <<= 1) {
            int u = __shfl_up(w, off);
            if (tid >= off) w += u;
        }
        wsum[tid] = w;
    }
    __syncthreads();
    int base = (wid > 0 ? wsum[wid - 1] : 0) + (v - local);
    int run = base;
    for (int i = i0; i < i1; ++i) {
        row_ptr[i] = run;
        run += degi[i];
    }
    if (tid == 0) row_ptr[N] = wsum[15];
}

// ---------------- CSR fill (bucket src by dst) + edge weight ----------------
__global__ void fill_kernel(const int* __restrict__ src, const int* __restrict__ dst,
                            const int* __restrict__ row_ptr, int* __restrict__ fill,
                            const float* __restrict__ nrm,
                            int* __restrict__ csr, float* __restrict__ wgt, int E) {
    int i = blockIdx.x * blockDim.x + threadIdx.x;
    if (i < E) {
        int d = dst[i];
        int s = src[i];
        int pos = row_ptr[d] + atomicAdd(&fill[d], 1);
        csr[pos] = s;
        wgt[pos] = nrm[s] * nrm[d];
    }
}

// ---------------- weight transpose + bf16 convert: Wt[l][n][k] ----------------
__global__ __launch_bounds__(256) void wcvt_kernel(const float* __restrict__ W,
                                                   unsigned short* __restrict__ Wt) {
    __shared__ float s[32][33];
    int l = blockIdx.z;
    int k0 = blockIdx.x * 32, n0 = blockIdx.y * 32;
    int c = threadIdx.x & 31, r8 = threadIdx.x >> 5;
    const float* Wl = W + (size_t)l * HID * HID;
    unsigned short* Wtl = Wt + (size_t)l * HID * HID;
#pragma unroll
    for (int p = 0; p < 4; ++p) {
        int r = r8 + p * 8;
        s[r][c] = Wl[(k0 + r) * HID + n0 + c];
    }
    __syncthreads();
#pragma unroll
    for (int p = 0; p < 4; ++p) {
        int r = r8 + p * 8;
        Wtl[(size_t)(n0 + r) * HID + k0 + c] = f2bf(s[c][r]);
    }
}

// ---------------- atom encoder: sum of 9 per-feature embeddings ----------------
__global__ __launch_bounds__(256) void embed_kernel(const int* __restrict__ x,
                                                    const float* __restrict__ emb,
                                                    float* __restrict__ h,
                                                    unsigned short* __restrict__ hb, int N) {
    int n = blockIdx.x;
    int c = threadIdx.x;
    __shared__ int xf[NFEAT];
    if (c < NFEAT) xf[c] = x[n * NFEAT + c];
    __syncthreads();
    float s = 0.f;
#pragma unroll
    for (int f = 0; f < NFEAT; ++f) s += emb[(size_t)(f * VOCAB + xf[f]) * HID + c];
    h[(size_t)n * HID + c] = s;
    hb[(size_t)n * HID + c] = f2bf(s);
}

// ---------------- GCN aggregate, XCD-sliced by column quarter -----------------
// blockIdx%8 -> XCD (round-robin dispatch); quarter = blockIdx&3 so XCD x only
// touches columns [64*(x%4), 64*(x%4)+64) -> 1.25 MB slice resident in 4 MiB L2.
// One wave per node per quarter, 1 bf16/lane (wave reads one 128B line per edge).
__global__ __launch_bounds__(256) void agg_q_kernel(const unsigned short* __restrict__ hb,
                                                    const int* __restrict__ row_ptr,
                                                    const int* __restrict__ csr,
                                                    const float* __restrict__ wgt,
                                                    const float* __restrict__ nrm,
                                                    unsigned short* __restrict__ aggb, int N) {
    int bx = blockIdx.x;
    int quarter = bx & 3;
    int n = (bx >> 2) * 4 + (threadIdx.x >> 6);
    if (n >= N) return;
    int c = quarter * 64 + (threadIdx.x & 63);
    int s = row_ptr[n], e = row_ptr[n + 1];
    float acc = 0.f;
    int i = s;
    for (; i + 3 < e; i += 4) {
        int s0 = csr[i], s1 = csr[i + 1], s2 = csr[i + 2], s3 = csr[i + 3];
        float w0 = wgt[i], w1 = wgt[i + 1], w2 = wgt[i + 2], w3 = wgt[i + 3];
        float v0 = bf2f(hb[(size_t)s0 * HID + c]);
        float v1 = bf2f(hb[(size_t)s1 * HID + c]);
        float v2 = bf2f(hb[(size_t)s2 * HID + c]);
        float v3 = bf2f(hb[(size_t)s3 * HID + c]);
        acc += w0 * v0 + w1 * v1 + w2 * v2 + w3 * v3;
    }
    for (; i < e; ++i) {
        int s0 = csr[i];
        acc += wgt[i] * bf2f(hb[(size_t)s0 * HID + c]);
    }
    float nd = nrm[n];
    acc += nd * nd * bf2f(hb[(size_t)n * HID + c]);
    aggb[(size_t)n * HID + c] = f2bf(acc);
}

// ---------------- bf16 MFMA GEMM + bias + fused BN column stats ----------------
__global__ __launch_bounds__(256) void mfma_gemm(const unsigned short* __restrict__ A,
                                                 const unsigned short* __restrict__ Bt,
                                                 const float* __restrict__ bias,
                                                 float* __restrict__ C,
                                                 float* __restrict__ sums, int M) {
    __shared__ unsigned short As[64][40];
    __shared__ unsigned short Bs[64][40];
    __shared__ float lsum[64];
    __shared__ float lsq[64];
    int tid = threadIdx.x;
    int row0 = blockIdx.x * 64;
    int col0 = blockIdx.y * 64;
    int lrow = tid >> 2;
    int lkc = (tid & 3) * 8;
    int lane = tid & 63;
    int wid = tid >> 6;
    int wm = (wid & 1) * 32;
    int wn = (wid >> 1) * 32;
    int quad = lane >> 4;
    int ln = lane & 15;

    floatx4 acc00 = {0.f, 0.f, 0.f, 0.f};
    floatx4 acc01 = {0.f, 0.f, 0.f, 0.f};
    floatx4 acc10 = {0.f, 0.f, 0.f, 0.f};
    floatx4 acc11 = {0.f, 0.f, 0.f, 0.f};

    if (tid < 64) { lsum[tid] = 0.f; lsq[tid] = 0.f; }

    for (int kk = 0; kk < HID; kk += 32) {
        short8 av = {0, 0, 0, 0, 0, 0, 0, 0};
        int ar = row0 + lrow;
        if (ar < M) av = *(const short8*)&A[(size_t)ar * HID + kk + lkc];
        short8 bv = *(const short8*)&Bt[(size_t)(col0 + lrow) * HID + kk + lkc];
        *(short8*)&As[lrow][lkc] = av;
        *(short8*)&Bs[lrow][lkc] = bv;
        __syncthreads();
        short8 a0 = *(const short8*)&As[wm + ln][quad * 8];
        short8 a1 = *(const short8*)&As[wm + 16 + ln][quad * 8];
        short8 b0 = *(const short8*)&Bs[wn + ln][quad * 8];
        short8 b1 = *(const short8*)&Bs[wn + 16 + ln][quad * 8];
        acc00 = __builtin_amdgcn_mfma_f32_16x16x32_bf16(a0, b0, acc00, 0, 0, 0);
        acc01 = __builtin_amdgcn_mfma_f32_16x16x32_bf16(a0, b1, acc01, 0, 0, 0);
        acc10 = __builtin_amdgcn_mfma_f32_16x16x32_bf16(a1, b0, acc10, 0, 0, 0);
        acc11 = __builtin_amdgcn_mfma_f32_16x16x32_bf16(a1, b1, acc11, 0, 0, 0);
        __syncthreads();
    }
    float bias0 = bias[col0 + wn + ln];
    float bias1 = bias[col0 + wn + 16 + ln];
    float p0 = 0.f, q0 = 0.f, p1 = 0.f, q1 = 0.f;
#pragma unroll
    for (int r = 0; r < 4; ++r) {
        int row = row0 + wm + quad * 4 + r;
        if (row < M) {
            float v0 = acc00[r] + bias0;
            float v1 = acc01[r] + bias1;
            C[(size_t)row * HID + col0 + wn + ln] = v0;
            C[(size_t)row * HID + col0 + wn + 16 + ln] = v1;
            p0 += v0; q0 += v0 * v0;
            p1 += v1; q1 += v1 * v1;
        }
        int row2 = row + 16;
        if (row2 < M) {
            float v0 = acc10[r] + bias0;
            float v1 = acc11[r] + bias1;
            C[(size_t)row2 * HID + col0 + wn + ln] = v0;
            C[(size_t)row2 * HID + col0 + wn + 16 + ln] = v1;
            p0 += v0; q0 += v0 * v0;
            p1 += v1; q1 += v1 * v1;
        }
    }
    atomicAdd(&lsum[wn + ln], p0);
    atomicAdd(&lsq[wn + ln], q0);
    atomicAdd(&lsum[wn + 16 + ln], p1);
    atomicAdd(&lsq[wn + 16 + ln], q1);
    __syncthreads();
    if (tid < 64) {
        unsafeAtomicAdd(&sums[col0 + tid], lsum[tid]);
        unsafeAtomicAdd(&sums[HID + col0 + tid], lsq[tid]);
    }
}

// ---------------- BN apply + relu + residual (+ bf16 copy), float4 ------------
__global__ __launch_bounds__(256) void bn_kernel(const float* __restrict__ hw,
                                                 const float* __restrict__ sums,
                                                 const float* __restrict__ gamma,
                                                 const float* __restrict__ beta,
                                                 const float* __restrict__ hold,
                                                 float* __restrict__ hnew,
                                                 unsigned short* __restrict__ hbnew, int N) {
    int i4 = blockIdx.x * blockDim.x + threadIdx.x;
    int base = i4 * 4;
    if (base >= N * HID) return;
    int c = base & (HID - 1);
    float invN = 1.0f / (float)N;
    float4 s4 = *(const float4*)&sums[c];
    float4 q4 = *(const float4*)&sums[HID + c];
    float4 g4 = *(const float4*)&gamma[c];
    float4 be4 = *(const float4*)&beta[c];
    float4 v = *(const float4*)&hw[base];
    float4 r = *(const float4*)&hold[base];
    float4 o;
    {
        float mu = s4.x * invN, var = q4.x * invN - mu * mu;
        o.x = fmaxf((v.x - mu) * g4.x * rsqrtf(var + BN_EPS) + be4.x, 0.f) + r.x;
        mu = s4.y * invN; var = q4.y * invN - mu * mu;
        o.y = fmaxf((v.y - mu) * g4.y * rsqrtf(var + BN_EPS) + be4.y, 0.f) + r.y;
        mu = s4.z * invN; var = q4.z * invN - mu * mu;
        o.z = fmaxf((v.z - mu) * g4.z * rsqrtf(var + BN_EPS) + be4.z, 0.f) + r.z;
        mu = s4.w * invN; var = q4.w * invN - mu * mu;
        o.w = fmaxf((v.w - mu) * g4.w * rsqrtf(var + BN_EPS) + be4.w, 0.f) + r.w;
    }
    *(float4*)&hnew[base] = o;
    ushort4 ob;
    ob.x = f2bf(o.x); ob.y = f2bf(o.y); ob.z = f2bf(o.z); ob.w = f2bf(o.w);
    *(ushort4*)&hbnew[base] = ob;
}

// ---------------- fused mean-pool (binary search on sorted batch) + MLP -------
__device__ inline int lower_bound_g(const int* __restrict__ a, int n, int key) {
    int lo = 0, hi = n;
    while (lo < hi) {
        int mid = (lo + hi) >> 1;
        if (a[mid] < key) lo = mid + 1; else hi = mid;
    }
    return lo;
}

__global__ __launch_bounds__(256) void pool_mlp_kernel(const float* __restrict__ h,
                                                       const int* __restrict__ batch, int N,
                                                       const float* __restrict__ W1,
                                                       const float* __restrict__ b1,
                                                       const float* __restrict__ W2,
                                                       const float* __restrict__ b2,
                                                       const float* __restrict__ W3,
                                                       const float* __restrict__ b3,
                                                       float* __restrict__ out) {
    int g = blockIdx.x, tid = threadIdx.x;
    int lo = lower_bound_g(batch, N, g);
    int hi = lower_bound_g(batch, N, g + 1);
    float s = 0.f;
    for (int i = lo; i < hi; ++i) s += h[(size_t)i * HID + tid];
    __shared__ float gs[256];
    __shared__ float t1[128];
    __shared__ float t2[64];
    float inv = 1.0f / fmaxf((float)(hi - lo), 1.0f);
    gs[tid] = s * inv;
    __syncthreads();
    if (tid < 128) {
        float a = b1[tid];
        for (int k = 0; k < 256; ++k) a += gs[k] * W1[k * 128 + tid];
        t1[tid] = fmaxf(a, 0.f);
    }
    __syncthreads();
    if (tid < 64) {
        float a = b2[tid];
        for (int k = 0; k < 128; ++k) a += t1[k] * W2[k * 64 + tid];
        t2[tid] = fmaxf(a, 0.f);
    }
    __syncthreads();
    if (tid < 64) {
        float p = t2[tid] * W3[tid];
#pragma unroll
        for (int off = 32; off >= 1; off >>= 1) p += __shfl_down(p, off);
        if (tid == 0) out[g] = p + b3[0];
    }
}

extern "C" void kernel_launch(void* const* d_in, const int* in_sizes, int n_in,
                              void* d_out, int out_size, void* d_ws, size_t ws_size,
                              hipStream_t stream) {
    const int* x      = (const int*)d_in[0];
    const int* ei     = (const int*)d_in[1];
    const int* batch  = (const int*)d_in[2];
    const float* emb  = (const float*)d_in[3];
    const float* W    = (const float*)d_in[4];
    const float* b    = (const float*)d_in[5];
    const float* gamma= (const float*)d_in[6];
    const float* beta = (const float*)d_in[7];
    const float* W1   = (const float*)d_in[8];
    const float* b1   = (const float*)d_in[9];
    const float* W2   = (const float*)d_in[10];
    const float* b2   = (const float*)d_in[11];
    const float* W3   = (const float*)d_in[12];
    const float* b3   = (const float*)d_in[13];
    float* out = (float*)d_out;

    int N = in_sizes[0] / NFEAT;
    int E = in_sizes[1] / 2;
    const int* srcp = ei;
    const int* dstp = ei + E;

    char* ws = (char*)d_ws;
    auto alloc = [&](size_t bytes) -> char* {
        char* p = ws;
        ws += (bytes + 255) & ~(size_t)255;
        return p;
    };
    int* degi     = (int*)alloc((size_t)N * 4);
    int* row_ptr  = (int*)alloc((size_t)(N + 1) * 4);
    int* fillc    = (int*)alloc((size_t)N * 4);
    float* nrm    = (float*)alloc((size_t)N * 4);
    int* csr      = (int*)alloc((size_t)E * 4);
    float* wgt    = (float*)alloc((size_t)E * 4);
    float* hA     = (float*)alloc((size_t)N * HID * 4);
    float* hB     = (float*)alloc((size_t)N * HID * 4);
    float* hw     = (float*)alloc((size_t)N * HID * 4);
    unsigned short* hbA  = (unsigned short*)alloc((size_t)N * HID * 2);
    unsigned short* hbB  = (unsigned short*)alloc((size_t)N * HID * 2);
    unsigned short* aggb = (unsigned short*)alloc((size_t)N * HID * 2);
    unsigned short* wt   = (unsigned short*)alloc((size_t)NLAYERS * HID * HID * 2);
    float* bnsums = (float*)alloc((size_t)NLAYERS * 2 * HID * 4);

    hipMemsetAsync(degi, 0, (size_t)N * 4, stream);
    hipMemsetAsync(fillc, 0, (size_t)N * 4, stream);
    hipMemsetAsync(bnsums, 0, (size_t)NLAYERS * 2 * HID * 4, stream);

    deg_kernel<<<(E + 255) / 256, 256, 0, stream>>>(dstp, degi, E);
    nrm_kernel<<<(N + 255) / 256, 256, 0, stream>>>(degi, nrm, N);
    scan_kernel<<<1, 1024, 0, stream>>>(degi, row_ptr, N);
    fill_kernel<<<(E + 255) / 256, 256, 0, stream>>>(srcp, dstp, row_ptr, fillc, nrm, csr, wgt, E);
    wcvt_kernel<<<dim3(8, 8, NLAYERS), 256, 0, stream>>>(W, wt);
    embed_kernel<<<N, 256, 0, stream>>>(x, emb, hA, hbA, N);

    float* hcur = hA;
    float* hoth = hB;
    unsigned short* hbcur = hbA;
    unsigned short* hboth = hbB;
    int aggGrid = ((N + 3) / 4) * 4;
    for (int l = 0; l < NLAYERS; ++l) {
        float* lsums = bnsums + (size_t)l * 2 * HID;
        agg_q_kernel<<<aggGrid, 256, 0, stream>>>(hbcur, row_ptr, csr, wgt, nrm, aggb, N);
        dim3 ggrid((N + 63) / 64, 4);
        mfma_gemm<<<ggrid, 256, 0, stream>>>(aggb, wt + (size_t)l * HID * HID,
                                             b + (size_t)l * HID, hw, lsums, N);
        bn_kernel<<<((size_t)N * HID / 4 + 255) / 256, 256, 0, stream>>>(
            hw, lsums, gamma + (size_t)l * HID, beta + (size_t)l * HID,
            hcur, hoth, hboth, N);
        float* t = hcur; hcur = hoth; hoth = t;
        unsigned short* tb = hbcur; hbcur = hboth; hboth = tb;
    }

    pool_mlp_kernel<<<NGRAPHS, 256, 0, stream>>>(hcur, batch, N, W1, b1, W2, b2, W3, b3, out);
}

// Round 5
// 363.501 us; speedup vs baseline: 1.1550x; 1.1550x over previous
//
#include <hip/hip_runtime.h>

#define HID 256
#define NFEAT 9
#define VOCAB 119
#define NLAYERS 4
#define NGRAPHS 256
#define BN_EPS 1e-5f

typedef short short8 __attribute__((ext_vector_type(8)));
typedef float floatx4 __attribute__((ext_vector_type(4)));

__device__ inline unsigned short f2bf(float f) {
    unsigned int u = __float_as_uint(f);
    unsigned int r = u + 0x7FFF + ((u >> 16) & 1);  // RNE
    return (unsigned short)(r >> 16);
}
__device__ inline float bf2f(unsigned short u) {
    return __uint_as_float(((unsigned int)u) << 16);
}

// ---------------- degree count (in-degree over dst) ----------------
__global__ void deg_kernel(const int* __restrict__ dst, int* __restrict__ degi, int E) {
    int i = blockIdx.x * blockDim.x + threadIdx.x;
    if (i < E) atomicAdd(&degi[dst[i]], 1);
}

__global__ void nrm_kernel(const int* __restrict__ degi, float* __restrict__ nrm, int N) {
    int i = blockIdx.x * blockDim.x + threadIdx.x;
    if (i < N) nrm[i] = rsqrtf(1.0f + (float)degi[i]);
}

// ---------------- parallel exclusive scan (single block, 1024 thr) ----------------
__global__ __launch_bounds__(1024) void scan_kernel(const int* __restrict__ degi,
                                                    int* __restrict__ row_ptr, int N) {
    int tid = threadIdx.x;
    int ch = (N + 1023) >> 10;
    int i0 = tid * ch;
    int i1 = min(i0 + ch, N);
    if (i0 > N) i0 = N;
    int local = 0;
    for (int i = i0; i < i1; ++i) local += degi[i];
    int lane = tid & 63, wid = tid >> 6;
    int v = local;
#pragma unroll
    for (int off = 1; off < 64; off <<= 1) {
        int u = __shfl_up(v, off);
        if (lane >= off) v += u;
    }
    __shared__ int wsum[16];
    if (lane == 63) wsum[wid] = v;
    __syncthreads();
    if (tid < 16) {
        int w = wsum[tid];
#pragma unroll
        for (int off = 1; off < 16; off <<= 1) {
            int u = __shfl_up(w, off);
            if (tid >= off) w += u;
        }
        wsum[tid] = w;
    }
    __syncthreads();
    int base = (wid > 0 ? wsum[wid - 1] : 0) + (v - local);
    int run = base;
    for (int i = i0; i < i1; ++i) {
        row_ptr[i] = run;
        run += degi[i];
    }
    if (tid == 0) row_ptr[N] = wsum[15];
}

// ---------------- CSR fill: interleaved (src, weight) edge records ----------------
__global__ void fill_kernel(const int* __restrict__ src, const int* __restrict__ dst,
                            const int* __restrict__ row_ptr, int* __restrict__ fill,
                            const float* __restrict__ nrm,
                            int2* __restrict__ edges, int E) {
    int i = blockIdx.x * blockDim.x + threadIdx.x;
    if (i < E) {
        int d = dst[i];
        int s = src[i];
        int pos = row_ptr[d] + atomicAdd(&fill[d], 1);
        int2 rec;
        rec.x = s;
        rec.y = __float_as_int(nrm[s] * nrm[d]);
        edges[pos] = rec;
    }
}

// ---------------- weight transpose + bf16 convert: Wt[l][n][k] ----------------
__global__ __launch_bounds__(256) void wcvt_kernel(const float* __restrict__ W,
                                                   unsigned short* __restrict__ Wt) {
    __shared__ float s[32][33];
    int l = blockIdx.z;
    int k0 = blockIdx.x * 32, n0 = blockIdx.y * 32;
    int c = threadIdx.x & 31, r8 = threadIdx.x >> 5;
    const float* Wl = W + (size_t)l * HID * HID;
    unsigned short* Wtl = Wt + (size_t)l * HID * HID;
#pragma unroll
    for (int p = 0; p < 4; ++p) {
        int r = r8 + p * 8;
        s[r][c] = Wl[(k0 + r) * HID + n0 + c];
    }
    __syncthreads();
#pragma unroll
    for (int p = 0; p < 4; ++p) {
        int r = r8 + p * 8;
        Wtl[(size_t)(n0 + r) * HID + k0 + c] = f2bf(s[c][r]);
    }
}

// ---------------- atom encoder: sum of 9 per-feature embeddings ----------------
__global__ __launch_bounds__(256) void embed_kernel(const int* __restrict__ x,
                                                    const float* __restrict__ emb,
                                                    float* __restrict__ h,
                                                    unsigned short* __restrict__ hb, int N) {
    int n = blockIdx.x;
    int c = threadIdx.x;
    __shared__ int xf[NFEAT];
    if (c < NFEAT) xf[c] = x[n * NFEAT + c];
    __syncthreads();
    float s = 0.f;
#pragma unroll
    for (int f = 0; f < NFEAT; ++f) s += emb[(size_t)(f * VOCAB + xf[f]) * HID + c];
    h[(size_t)n * HID + c] = s;
    hb[(size_t)n * HID + c] = f2bf(s);
}

// ---------------- GCN aggregate, XCD-sliced by column HALF --------------------
// blockIdx%8 -> XCD (round-robin); half = blockIdx&1 is constant per XCD, so
// each XCD's L2 holds a 128-col x 10000-row bf16 slice = 2.5 MB (fits 4 MiB).
// One wave per (node, half): lane loads ushort2 (4B) -> 256B/wave per edge.
__global__ __launch_bounds__(256) void agg_h_kernel(const unsigned short* __restrict__ hb,
                                                    const int* __restrict__ row_ptr,
                                                    const int2* __restrict__ edges,
                                                    const float* __restrict__ nrm,
                                                    unsigned short* __restrict__ aggb, int N) {
    int bx = blockIdx.x;
    int half = bx & 1;
    int n = (bx >> 1) * 4 + (threadIdx.x >> 6);
    if (n >= N) return;
    int c = half * 128 + (threadIdx.x & 63) * 2;
    const unsigned short* hbc = hb + c;
    int s = row_ptr[n], e = row_ptr[n + 1];
    float ax = 0.f, ay = 0.f;
    int i = s;
    for (; i + 3 < e; i += 4) {
        int2 e0 = edges[i], e1 = edges[i + 1], e2 = edges[i + 2], e3 = edges[i + 3];
        ushort2 u0 = *(const ushort2*)&hbc[(size_t)e0.x * HID];
        ushort2 u1 = *(const ushort2*)&hbc[(size_t)e1.x * HID];
        ushort2 u2 = *(const ushort2*)&hbc[(size_t)e2.x * HID];
        ushort2 u3 = *(const ushort2*)&hbc[(size_t)e3.x * HID];
        float w0 = __int_as_float(e0.y), w1 = __int_as_float(e1.y);
        float w2 = __int_as_float(e2.y), w3 = __int_as_float(e3.y);
        ax += w0 * bf2f(u0.x) + w1 * bf2f(u1.x) + w2 * bf2f(u2.x) + w3 * bf2f(u3.x);
        ay += w0 * bf2f(u0.y) + w1 * bf2f(u1.y) + w2 * bf2f(u2.y) + w3 * bf2f(u3.y);
    }
    for (; i < e; ++i) {
        int2 e0 = edges[i];
        ushort2 u0 = *(const ushort2*)&hbc[(size_t)e0.x * HID];
        float w0 = __int_as_float(e0.y);
        ax += w0 * bf2f(u0.x);
        ay += w0 * bf2f(u0.y);
    }
    float nd = nrm[n];
    float sw = nd * nd;
    ushort2 us = *(const ushort2*)&hbc[(size_t)n * HID];
    ax += sw * bf2f(us.x);
    ay += sw * bf2f(us.y);
    ushort2 o;
    o.x = f2bf(ax);
    o.y = f2bf(ay);
    *(ushort2*)&aggb[(size_t)n * HID + c] = o;
}

// ---------------- bf16 MFMA GEMM + bias + fused BN column stats ----------------
__global__ __launch_bounds__(256) void mfma_gemm(const unsigned short* __restrict__ A,
                                                 const unsigned short* __restrict__ Bt,
                                                 const float* __restrict__ bias,
                                                 float* __restrict__ C,
                                                 float* __restrict__ sums, int M) {
    __shared__ unsigned short As[64][40];
    __shared__ unsigned short Bs[64][40];
    __shared__ float lsum[64];
    __shared__ float lsq[64];
    int tid = threadIdx.x;
    int row0 = blockIdx.x * 64;
    int col0 = blockIdx.y * 64;
    int lrow = tid >> 2;
    int lkc = (tid & 3) * 8;
    int lane = tid & 63;
    int wid = tid >> 6;
    int wm = (wid & 1) * 32;
    int wn = (wid >> 1) * 32;
    int quad = lane >> 4;
    int ln = lane & 15;

    floatx4 acc00 = {0.f, 0.f, 0.f, 0.f};
    floatx4 acc01 = {0.f, 0.f, 0.f, 0.f};
    floatx4 acc10 = {0.f, 0.f, 0.f, 0.f};
    floatx4 acc11 = {0.f, 0.f, 0.f, 0.f};

    if (tid < 64) { lsum[tid] = 0.f; lsq[tid] = 0.f; }

    for (int kk = 0; kk < HID; kk += 32) {
        short8 av = {0, 0, 0, 0, 0, 0, 0, 0};
        int ar = row0 + lrow;
        if (ar < M) av = *(const short8*)&A[(size_t)ar * HID + kk + lkc];
        short8 bv = *(const short8*)&Bt[(size_t)(col0 + lrow) * HID + kk + lkc];
        *(short8*)&As[lrow][lkc] = av;
        *(short8*)&Bs[lrow][lkc] = bv;
        __syncthreads();
        short8 a0 = *(const short8*)&As[wm + ln][quad * 8];
        short8 a1 = *(const short8*)&As[wm + 16 + ln][quad * 8];
        short8 b0 = *(const short8*)&Bs[wn + ln][quad * 8];
        short8 b1 = *(const short8*)&Bs[wn + 16 + ln][quad * 8];
        acc00 = __builtin_amdgcn_mfma_f32_16x16x32_bf16(a0, b0, acc00, 0, 0, 0);
        acc01 = __builtin_amdgcn_mfma_f32_16x16x32_bf16(a0, b1, acc01, 0, 0, 0);
        acc10 = __builtin_amdgcn_mfma_f32_16x16x32_bf16(a1, b0, acc10, 0, 0, 0);
        acc11 = __builtin_amdgcn_mfma_f32_16x16x32_bf16(a1, b1, acc11, 0, 0, 0);
        __syncthreads();
    }
    float bias0 = bias[col0 + wn + ln];
    float bias1 = bias[col0 + wn + 16 + ln];
    float p0 = 0.f, q0 = 0.f, p1 = 0.f, q1 = 0.f;
#pragma unroll
    for (int r = 0; r < 4; ++r) {
        int row = row0 + wm + quad * 4 + r;
        if (row < M) {
            float v0 = acc00[r] + bias0;
            float v1 = acc01[r] + bias1;
            C[(size_t)row * HID + col0 + wn + ln] = v0;
            C[(size_t)row * HID + col0 + wn + 16 + ln] = v1;
            p0 += v0; q0 += v0 * v0;
            p1 += v1; q1 += v1 * v1;
        }
        int row2 = row + 16;
        if (row2 < M) {
            float v0 = acc10[r] + bias0;
            float v1 = acc11[r] + bias1;
            C[(size_t)row2 * HID + col0 + wn + ln] = v0;
            C[(size_t)row2 * HID + col0 + wn + 16 + ln] = v1;
            p0 += v0; q0 += v0 * v0;
            p1 += v1; q1 += v1 * v1;
        }
    }
    atomicAdd(&lsum[wn + ln], p0);
    atomicAdd(&lsq[wn + ln], q0);
    atomicAdd(&lsum[wn + 16 + ln], p1);
    atomicAdd(&lsq[wn + 16 + ln], q1);
    __syncthreads();
    if (tid < 64) {
        unsafeAtomicAdd(&sums[col0 + tid], lsum[tid]);
        unsafeAtomicAdd(&sums[HID + col0 + tid], lsq[tid]);
    }
}

// ---------------- BN apply + relu + residual (+ bf16 copy), float4 ------------
__global__ __launch_bounds__(256) void bn_kernel(const float* __restrict__ hw,
                                                 const float* __restrict__ sums,
                                                 const float* __restrict__ gamma,
                                                 const float* __restrict__ beta,
                                                 const float* __restrict__ hold,
                                                 float* __restrict__ hnew,
                                                 unsigned short* __restrict__ hbnew, int N) {
    int i4 = blockIdx.x * blockDim.x + threadIdx.x;
    int base = i4 * 4;
    if (base >= N * HID) return;
    int c = base & (HID - 1);
    float invN = 1.0f / (float)N;
    float4 s4 = *(const float4*)&sums[c];
    float4 q4 = *(const float4*)&sums[HID + c];
    float4 g4 = *(const float4*)&gamma[c];
    float4 be4 = *(const float4*)&beta[c];
    float4 v = *(const float4*)&hw[base];
    float4 r = *(const float4*)&hold[base];
    float4 o;
    {
        float mu = s4.x * invN, var = q4.x * invN - mu * mu;
        o.x = fmaxf((v.x - mu) * g4.x * rsqrtf(var + BN_EPS) + be4.x, 0.f) + r.x;
        mu = s4.y * invN; var = q4.y * invN - mu * mu;
        o.y = fmaxf((v.y - mu) * g4.y * rsqrtf(var + BN_EPS) + be4.y, 0.f) + r.y;
        mu = s4.z * invN; var = q4.z * invN - mu * mu;
        o.z = fmaxf((v.z - mu) * g4.z * rsqrtf(var + BN_EPS) + be4.z, 0.f) + r.z;
        mu = s4.w * invN; var = q4.w * invN - mu * mu;
        o.w = fmaxf((v.w - mu) * g4.w * rsqrtf(var + BN_EPS) + be4.w, 0.f) + r.w;
    }
    *(float4*)&hnew[base] = o;
    ushort4 ob;
    ob.x = f2bf(o.x); ob.y = f2bf(o.y); ob.z = f2bf(o.z); ob.w = f2bf(o.w);
    *(ushort4*)&hbnew[base] = ob;
}

// ---------------- fused mean-pool (binary search on sorted batch) + MLP -------
__device__ inline int lower_bound_g(const int* __restrict__ a, int n, int key) {
    int lo = 0, hi = n;
    while (lo < hi) {
        int mid = (lo + hi) >> 1;
        if (a[mid] < key) lo = mid + 1; else hi = mid;
    }
    return lo;
}

__global__ __launch_bounds__(256) void pool_mlp_kernel(const float* __restrict__ h,
                                                       const int* __restrict__ batch, int N,
                                                       const float* __restrict__ W1,
                                                       const float* __restrict__ b1,
                                                       const float* __restrict__ W2,
                                                       const float* __restrict__ b2,
                                                       const float* __restrict__ W3,
                                                       const float* __restrict__ b3,
                                                       float* __restrict__ out) {
    int g = blockIdx.x, tid = threadIdx.x;
    int lo = lower_bound_g(batch, N, g);
    int hi = lower_bound_g(batch, N, g + 1);
    float s = 0.f;
    for (int i = lo; i < hi; ++i) s += h[(size_t)i * HID + tid];
    __shared__ float gs[256];
    __shared__ float t1[128];
    __shared__ float t2[64];
    float inv = 1.0f / fmaxf((float)(hi - lo), 1.0f);
    gs[tid] = s * inv;
    __syncthreads();
    if (tid < 128) {
        float a = b1[tid];
        for (int k = 0; k < 256; ++k) a += gs[k] * W1[k * 128 + tid];
        t1[tid] = fmaxf(a, 0.f);
    }
    __syncthreads();
    if (tid < 64) {
        float a = b2[tid];
        for (int k = 0; k < 128; ++k) a += t1[k] * W2[k * 64 + tid];
        t2[tid] = fmaxf(a, 0.f);
    }
    __syncthreads();
    if (tid < 64) {
        float p = t2[tid] * W3[tid];
#pragma unroll
        for (int off = 32; off >= 1; off >>= 1) p += __shfl_down(p, off);
        if (tid == 0) out[g] = p + b3[0];
    }
}

extern "C" void kernel_launch(void* const* d_in, const int* in_sizes, int n_in,
                              void* d_out, int out_size, void* d_ws, size_t ws_size,
                              hipStream_t stream) {
    const int* x      = (const int*)d_in[0];
    const int* ei     = (const int*)d_in[1];
    const int* batch  = (const int*)d_in[2];
    const float* emb  = (const float*)d_in[3];
    const float* W    = (const float*)d_in[4];
    const float* b    = (const float*)d_in[5];
    const float* gamma= (const float*)d_in[6];
    const float* beta = (const float*)d_in[7];
    const float* W1   = (const float*)d_in[8];
    const float* b1   = (const float*)d_in[9];
    const float* W2   = (const float*)d_in[10];
    const float* b2   = (const float*)d_in[11];
    const float* W3   = (const float*)d_in[12];
    const float* b3   = (const float*)d_in[13];
    float* out = (float*)d_out;

    int N = in_sizes[0] / NFEAT;
    int E = in_sizes[1] / 2;
    const int* srcp = ei;
    const int* dstp = ei + E;

    char* ws = (char*)d_ws;
    auto alloc = [&](size_t bytes) -> char* {
        char* p = ws;
        ws += (bytes + 255) & ~(size_t)255;
        return p;
    };
    int* degi     = (int*)alloc((size_t)N * 4);
    int* row_ptr  = (int*)alloc((size_t)(N + 1) * 4);
    int* fillc    = (int*)alloc((size_t)N * 4);
    float* nrm    = (float*)alloc((size_t)N * 4);
    int2* edges   = (int2*)alloc((size_t)E * 8);
    float* hA     = (float*)alloc((size_t)N * HID * 4);
    float* hB     = (float*)alloc((size_t)N * HID * 4);
    float* hw     = (float*)alloc((size_t)N * HID * 4);
    unsigned short* hbA  = (unsigned short*)alloc((size_t)N * HID * 2);
    unsigned short* hbB  = (unsigned short*)alloc((size_t)N * HID * 2);
    unsigned short* aggb = (unsigned short*)alloc((size_t)N * HID * 2);
    unsigned short* wt   = (unsigned short*)alloc((size_t)NLAYERS * HID * HID * 2);
    float* bnsums = (float*)alloc((size_t)NLAYERS * 2 * HID * 4);

    hipMemsetAsync(degi, 0, (size_t)N * 4, stream);
    hipMemsetAsync(fillc, 0, (size_t)N * 4, stream);
    hipMemsetAsync(bnsums, 0, (size_t)NLAYERS * 2 * HID * 4, stream);

    deg_kernel<<<(E + 255) / 256, 256, 0, stream>>>(dstp, degi, E);
    nrm_kernel<<<(N + 255) / 256, 256, 0, stream>>>(degi, nrm, N);
    scan_kernel<<<1, 1024, 0, stream>>>(degi, row_ptr, N);
    fill_kernel<<<(E + 255) / 256, 256, 0, stream>>>(srcp, dstp, row_ptr, fillc, nrm, edges, E);
    wcvt_kernel<<<dim3(8, 8, NLAYERS), 256, 0, stream>>>(W, wt);
    embed_kernel<<<N, 256, 0, stream>>>(x, emb, hA, hbA, N);

    float* hcur = hA;
    float* hoth = hB;
    unsigned short* hbcur = hbA;
    unsigned short* hboth = hbB;
    int aggGrid = ((N + 3) / 4) * 2;
    for (int l = 0; l < NLAYERS; ++l) {
        float* lsums = bnsums + (size_t)l * 2 * HID;
        agg_h_kernel<<<aggGrid, 256, 0, stream>>>(hbcur, row_ptr, edges, nrm, aggb, N);
        dim3 ggrid((N + 63) / 64, 4);
        mfma_gemm<<<ggrid, 256, 0, stream>>>(aggb, wt + (size_t)l * HID * HID,
                                             b + (size_t)l * HID, hw, lsums, N);
        bn_kernel<<<((size_t)N * HID / 4 + 255) / 256, 256, 0, stream>>>(
            hw, lsums, gamma + (size_t)l * HID, beta + (size_t)l * HID,
            hcur, hoth, hboth, N);
        float* t = hcur; hcur = hoth; hoth = t;
        unsigned short* tb = hbcur; hbcur = hboth; hboth = tb;
    }

    pool_mlp_kernel<<<NGRAPHS, 256, 0, stream>>>(hcur, batch, N, W1, b1, W2, b2, W3, b3, out);
}

// Round 6
// 359.576 us; speedup vs baseline: 1.1676x; 1.0109x over previous
//
#include <hip/hip_runtime.h>

#define HID 256
#define NFEAT 9
#define VOCAB 119
#define NLAYERS 4
#define NGRAPHS 256
#define BN_EPS 1e-5f
#define EPAD 256

typedef short short8 __attribute__((ext_vector_type(8)));
typedef float floatx4 __attribute__((ext_vector_type(4)));

__device__ inline unsigned short f2bf(float f) {
    unsigned int u = __float_as_uint(f);
    unsigned int r = u + 0x7FFF + ((u >> 16) & 1);  // RNE
    return (unsigned short)(r >> 16);
}
__device__ inline float bf2f(unsigned short u) {
    return __uint_as_float(((unsigned int)u) << 16);
}

// ---------------- degree count (in-degree over dst) ----------------
__global__ void deg_kernel(const int* __restrict__ dst, int* __restrict__ degi, int E) {
    int i = blockIdx.x * blockDim.x + threadIdx.x;
    if (i < E) atomicAdd(&degi[dst[i]], 1);
}

__global__ void nrm_kernel(const int* __restrict__ degi, float* __restrict__ nrm, int N) {
    int i = blockIdx.x * blockDim.x + threadIdx.x;
    if (i < N) nrm[i] = rsqrtf(1.0f + (float)degi[i]);
}

// ---------------- parallel exclusive scan (single block, 1024 thr) ----------------
__global__ __launch_bounds__(1024) void scan_kernel(const int* __restrict__ degi,
                                                    int* __restrict__ row_ptr, int N) {
    int tid = threadIdx.x;
    int ch = (N + 1023) >> 10;
    int i0 = tid * ch;
    int i1 = min(i0 + ch, N);
    if (i0 > N) i0 = N;
    int local = 0;
    for (int i = i0; i < i1; ++i) local += degi[i];
    int lane = tid & 63, wid = tid >> 6;
    int v = local;
#pragma unroll
    for (int off = 1; off < 64; off <<= 1) {
        int u = __shfl_up(v, off);
        if (lane >= off) v += u;
    }
    __shared__ int wsum[16];
    if (lane == 63) wsum[wid] = v;
    __syncthreads();
    if (tid < 16) {
        int w = wsum[tid];
#pragma unroll
        for (int off = 1; off < 16; off <<= 1) {
            int u = __shfl_up(w, off);
            if (tid >= off) w += u;
        }
        wsum[tid] = w;
    }
    __syncthreads();
    int base = (wid > 0 ? wsum[wid - 1] : 0) + (v - local);
    int run = base;
    for (int i = i0; i < i1; ++i) {
        row_ptr[i] = run;
        run += degi[i];
    }
    if (tid == 0) row_ptr[N] = wsum[15];
}

// ---------------- CSR fill: interleaved (src, weight) edge records ----------------
__global__ void fill_kernel(const int* __restrict__ src, const int* __restrict__ dst,
                            const int* __restrict__ row_ptr, int* __restrict__ fill,
                            const float* __restrict__ nrm,
                            int2* __restrict__ edges, int E) {
    int i = blockIdx.x * blockDim.x + threadIdx.x;
    if (i < E) {
        int d = dst[i];
        int s = src[i];
        int pos = row_ptr[d] + atomicAdd(&fill[d], 1);
        int2 rec;
        rec.x = s;
        rec.y = __float_as_int(nrm[s] * nrm[d]);
        edges[pos] = rec;
    }
}

// ---------------- weight transpose + bf16 convert: Wt[l][n][k] ----------------
__global__ __launch_bounds__(256) void wcvt_kernel(const float* __restrict__ W,
                                                   unsigned short* __restrict__ Wt) {
    __shared__ float s[32][33];
    int l = blockIdx.z;
    int k0 = blockIdx.x * 32, n0 = blockIdx.y * 32;
    int c = threadIdx.x & 31, r8 = threadIdx.x >> 5;
    const float* Wl = W + (size_t)l * HID * HID;
    unsigned short* Wtl = Wt + (size_t)l * HID * HID;
#pragma unroll
    for (int p = 0; p < 4; ++p) {
        int r = r8 + p * 8;
        s[r][c] = Wl[(k0 + r) * HID + n0 + c];
    }
    __syncthreads();
#pragma unroll
    for (int p = 0; p < 4; ++p) {
        int r = r8 + p * 8;
        Wtl[(size_t)(n0 + r) * HID + k0 + c] = f2bf(s[c][r]);
    }
}

// ---------------- atom encoder: sum of 9 per-feature embeddings ----------------
__global__ __launch_bounds__(256) void embed_kernel(const int* __restrict__ x,
                                                    const float* __restrict__ emb,
                                                    unsigned short* __restrict__ hb, int N) {
    int n = blockIdx.x;
    int c = threadIdx.x;
    __shared__ int xf[NFEAT];
    if (c < NFEAT) xf[c] = x[n * NFEAT + c];
    __syncthreads();
    float s = 0.f;
#pragma unroll
    for (int f = 0; f < NFEAT; ++f) s += emb[(size_t)(f * VOCAB + xf[f]) * HID + c];
    hb[(size_t)n * HID + c] = f2bf(s);
}

// ---------------- GCN aggregate: XCD half-slice, 2 nodes per wave -------------
// blockIdx%8 -> XCD; half = bx&1 constant per XCD -> 2.5 MB hb slice L2-resident.
// Wave: lanes 0-31 = node A, 32-63 = node B; lane covers 4 cols (ushort4, 8B).
// Branch-free predication: out-of-range iterations get w=0 (edges zero-padded).
__global__ __launch_bounds__(256) void agg_pair_kernel(const unsigned short* __restrict__ hb,
                                                       const int* __restrict__ row_ptr,
                                                       const int2* __restrict__ edges,
                                                       const float* __restrict__ nrm,
                                                       unsigned short* __restrict__ aggb, int N) {
    int bx = blockIdx.x;
    int half = bx & 1;
    int tid = threadIdx.x;
    int wave = tid >> 6;
    int lane = tid & 63;
    int sub = lane >> 5;
    int sl = lane & 31;
    int n = (bx >> 1) * 8 + wave * 2 + sub;
    bool nvalid = n < N;
    int nn = nvalid ? n : N - 1;
    int c = half * 128 + sl * 4;
    const unsigned short* hbc = hb + c;
    int s = row_ptr[nn], e = row_ptr[nn + 1];
    int len = e - s;
    int maxLen = max(len, __shfl_xor(len, 32));
    float a0 = 0.f, a1 = 0.f, a2 = 0.f, a3 = 0.f;
    for (int it = 0; it < maxLen; it += 2) {
        int2 e0 = edges[s + it];
        int2 e1 = edges[s + it + 1];
        float w0 = (it < len) ? __int_as_float(e0.y) : 0.f;
        float w1 = (it + 1 < len) ? __int_as_float(e1.y) : 0.f;
        ushort4 u0 = *(const ushort4*)&hbc[(size_t)e0.x * HID];
        ushort4 u1 = *(const ushort4*)&hbc[(size_t)e1.x * HID];
        a0 += w0 * bf2f(u0.x) + w1 * bf2f(u1.x);
        a1 += w0 * bf2f(u0.y) + w1 * bf2f(u1.y);
        a2 += w0 * bf2f(u0.z) + w1 * bf2f(u1.z);
        a3 += w0 * bf2f(u0.w) + w1 * bf2f(u1.w);
    }
    float nd = nrm[nn];
    float sw = nd * nd;
    ushort4 us = *(const ushort4*)&hbc[(size_t)nn * HID];
    a0 += sw * bf2f(us.x);
    a1 += sw * bf2f(us.y);
    a2 += sw * bf2f(us.z);
    a3 += sw * bf2f(us.w);
    if (nvalid) {
        ushort4 o;
        o.x = f2bf(a0); o.y = f2bf(a1); o.z = f2bf(a2); o.w = f2bf(a3);
        *(ushort4*)&aggb[(size_t)nn * HID + c] = o;
    }
}

// ---------------- bf16 MFMA GEMM + bias + fused BN column stats ----------------
// Output hw in bf16 (stats computed on fp32 pre-rounding values).
__global__ __launch_bounds__(256) void mfma_gemm(const unsigned short* __restrict__ A,
                                                 const unsigned short* __restrict__ Bt,
                                                 const float* __restrict__ bias,
                                                 unsigned short* __restrict__ C,
                                                 float* __restrict__ sums, int M) {
    __shared__ unsigned short As[64][40];
    __shared__ unsigned short Bs[64][40];
    __shared__ float lsum[64];
    __shared__ float lsq[64];
    int tid = threadIdx.x;
    int row0 = blockIdx.x * 64;
    int col0 = blockIdx.y * 64;
    int lrow = tid >> 2;
    int lkc = (tid & 3) * 8;
    int lane = tid & 63;
    int wid = tid >> 6;
    int wm = (wid & 1) * 32;
    int wn = (wid >> 1) * 32;
    int quad = lane >> 4;
    int ln = lane & 15;

    floatx4 acc00 = {0.f, 0.f, 0.f, 0.f};
    floatx4 acc01 = {0.f, 0.f, 0.f, 0.f};
    floatx4 acc10 = {0.f, 0.f, 0.f, 0.f};
    floatx4 acc11 = {0.f, 0.f, 0.f, 0.f};

    if (tid < 64) { lsum[tid] = 0.f; lsq[tid] = 0.f; }

    for (int kk = 0; kk < HID; kk += 32) {
        short8 av = {0, 0, 0, 0, 0, 0, 0, 0};
        int ar = row0 + lrow;
        if (ar < M) av = *(const short8*)&A[(size_t)ar * HID + kk + lkc];
        short8 bv = *(const short8*)&Bt[(size_t)(col0 + lrow) * HID + kk + lkc];
        *(short8*)&As[lrow][lkc] = av;
        *(short8*)&Bs[lrow][lkc] = bv;
        __syncthreads();
        short8 a0 = *(const short8*)&As[wm + ln][quad * 8];
        short8 a1 = *(const short8*)&As[wm + 16 + ln][quad * 8];
        short8 b0 = *(const short8*)&Bs[wn + ln][quad * 8];
        short8 b1 = *(const short8*)&Bs[wn + 16 + ln][quad * 8];
        acc00 = __builtin_amdgcn_mfma_f32_16x16x32_bf16(a0, b0, acc00, 0, 0, 0);
        acc01 = __builtin_amdgcn_mfma_f32_16x16x32_bf16(a0, b1, acc01, 0, 0, 0);
        acc10 = __builtin_amdgcn_mfma_f32_16x16x32_bf16(a1, b0, acc10, 0, 0, 0);
        acc11 = __builtin_amdgcn_mfma_f32_16x16x32_bf16(a1, b1, acc11, 0, 0, 0);
        __syncthreads();
    }
    float bias0 = bias[col0 + wn + ln];
    float bias1 = bias[col0 + wn + 16 + ln];
    float p0 = 0.f, q0 = 0.f, p1 = 0.f, q1 = 0.f;
#pragma unroll
    for (int r = 0; r < 4; ++r) {
        int row = row0 + wm + quad * 4 + r;
        if (row < M) {
            float v0 = acc00[r] + bias0;
            float v1 = acc01[r] + bias1;
            C[(size_t)row * HID + col0 + wn + ln] = f2bf(v0);
            C[(size_t)row * HID + col0 + wn + 16 + ln] = f2bf(v1);
            p0 += v0; q0 += v0 * v0;
            p1 += v1; q1 += v1 * v1;
        }
        int row2 = row + 16;
        if (row2 < M) {
            float v0 = acc10[r] + bias0;
            float v1 = acc11[r] + bias1;
            C[(size_t)row2 * HID + col0 + wn + ln] = f2bf(v0);
            C[(size_t)row2 * HID + col0 + wn + 16 + ln] = f2bf(v1);
            p0 += v0; q0 += v0 * v0;
            p1 += v1; q1 += v1 * v1;
        }
    }
    atomicAdd(&lsum[wn + ln], p0);
    atomicAdd(&lsq[wn + ln], q0);
    atomicAdd(&lsum[wn + 16 + ln], p1);
    atomicAdd(&lsq[wn + 16 + ln], q1);
    __syncthreads();
    if (tid < 64) {
        unsafeAtomicAdd(&sums[col0 + tid], lsum[tid]);
        unsafeAtomicAdd(&sums[HID + col0 + tid], lsq[tid]);
    }
}

// ---------------- BN apply + relu + residual, all bf16 ------------------------
__global__ __launch_bounds__(256) void bn_kernel(const unsigned short* __restrict__ hwb,
                                                 const float* __restrict__ sums,
                                                 const float* __restrict__ gamma,
                                                 const float* __restrict__ beta,
                                                 const unsigned short* __restrict__ hold,
                                                 unsigned short* __restrict__ hbnew, int N) {
    int i4 = blockIdx.x * blockDim.x + threadIdx.x;
    int base = i4 * 4;
    if (base >= N * HID) return;
    int c = base & (HID - 1);
    float invN = 1.0f / (float)N;
    float4 s4 = *(const float4*)&sums[c];
    float4 q4 = *(const float4*)&sums[HID + c];
    float4 g4 = *(const float4*)&gamma[c];
    float4 be4 = *(const float4*)&beta[c];
    ushort4 v = *(const ushort4*)&hwb[base];
    ushort4 r = *(const ushort4*)&hold[base];
    ushort4 o;
    {
        float mu = s4.x * invN, var = q4.x * invN - mu * mu;
        o.x = f2bf(fmaxf((bf2f(v.x) - mu) * g4.x * rsqrtf(var + BN_EPS) + be4.x, 0.f) + bf2f(r.x));
        mu = s4.y * invN; var = q4.y * invN - mu * mu;
        o.y = f2bf(fmaxf((bf2f(v.y) - mu) * g4.y * rsqrtf(var + BN_EPS) + be4.y, 0.f) + bf2f(r.y));
        mu = s4.z * invN; var = q4.z * invN - mu * mu;
        o.z = f2bf(fmaxf((bf2f(v.z) - mu) * g4.z * rsqrtf(var + BN_EPS) + be4.z, 0.f) + bf2f(r.z));
        mu = s4.w * invN; var = q4.w * invN - mu * mu;
        o.w = f2bf(fmaxf((bf2f(v.w) - mu) * g4.w * rsqrtf(var + BN_EPS) + be4.w, 0.f) + bf2f(r.w));
    }
    *(ushort4*)&hbnew[base] = o;
}

// ---------------- fused mean-pool (binary search on sorted batch) + MLP -------
__device__ inline int lower_bound_g(const int* __restrict__ a, int n, int key) {
    int lo = 0, hi = n;
    while (lo < hi) {
        int mid = (lo + hi) >> 1;
        if (a[mid] < key) lo = mid + 1; else hi = mid;
    }
    return lo;
}

__global__ __launch_bounds__(256) void pool_mlp_kernel(const unsigned short* __restrict__ h,
                                                       const int* __restrict__ batch, int N,
                                                       const float* __restrict__ W1,
                                                       const float* __restrict__ b1,
                                                       const float* __restrict__ W2,
                                                       const float* __restrict__ b2,
                                                       const float* __restrict__ W3,
                                                       const float* __restrict__ b3,
                                                       float* __restrict__ out) {
    int g = blockIdx.x, tid = threadIdx.x;
    int lo = lower_bound_g(batch, N, g);
    int hi = lower_bound_g(batch, N, g + 1);
    float s = 0.f;
    for (int i = lo; i < hi; ++i) s += bf2f(h[(size_t)i * HID + tid]);
    __shared__ float gs[256];
    __shared__ float t1[128];
    __shared__ float t2[64];
    float inv = 1.0f / fmaxf((float)(hi - lo), 1.0f);
    gs[tid] = s * inv;
    __syncthreads();
    if (tid < 128) {
        float a = b1[tid];
        for (int k = 0; k < 256; ++k) a += gs[k] * W1[k * 128 + tid];
        t1[tid] = fmaxf(a, 0.f);
    }
    __syncthreads();
    if (tid < 64) {
        float a = b2[tid];
        for (int k = 0; k < 128; ++k) a += t1[k] * W2[k * 64 + tid];
        t2[tid] = fmaxf(a, 0.f);
    }
    __syncthreads();
    if (tid < 64) {
        float p = t2[tid] * W3[tid];
#pragma unroll
        for (int off = 32; off >= 1; off >>= 1) p += __shfl_down(p, off);
        if (tid == 0) out[g] = p + b3[0];
    }
}

extern "C" void kernel_launch(void* const* d_in, const int* in_sizes, int n_in,
                              void* d_out, int out_size, void* d_ws, size_t ws_size,
                              hipStream_t stream) {
    const int* x      = (const int*)d_in[0];
    const int* ei     = (const int*)d_in[1];
    const int* batch  = (const int*)d_in[2];
    const float* emb  = (const float*)d_in[3];
    const float* W    = (const float*)d_in[4];
    const float* b    = (const float*)d_in[5];
    const float* gamma= (const float*)d_in[6];
    const float* beta = (const float*)d_in[7];
    const float* W1   = (const float*)d_in[8];
    const float* b1   = (const float*)d_in[9];
    const float* W2   = (const float*)d_in[10];
    const float* b2   = (const float*)d_in[11];
    const float* W3   = (const float*)d_in[12];
    const float* b3   = (const float*)d_in[13];
    float* out = (float*)d_out;

    int N = in_sizes[0] / NFEAT;
    int E = in_sizes[1] / 2;
    const int* srcp = ei;
    const int* dstp = ei + E;

    char* ws = (char*)d_ws;
    auto alloc = [&](size_t bytes) -> char* {
        char* p = ws;
        ws += (bytes + 255) & ~(size_t)255;
        return p;
    };
    int* degi     = (int*)alloc((size_t)N * 4);
    int* row_ptr  = (int*)alloc((size_t)(N + 1) * 4);
    int* fillc    = (int*)alloc((size_t)N * 4);
    float* nrm    = (float*)alloc((size_t)N * 4);
    int2* edges   = (int2*)alloc(((size_t)E + EPAD) * 8);
    unsigned short* hbA  = (unsigned short*)alloc((size_t)N * HID * 2);
    unsigned short* hbB  = (unsigned short*)alloc((size_t)N * HID * 2);
    unsigned short* aggb = (unsigned short*)alloc((size_t)N * HID * 2);
    unsigned short* hwb  = (unsigned short*)alloc((size_t)N * HID * 2);
    unsigned short* wt   = (unsigned short*)alloc((size_t)NLAYERS * HID * HID * 2);
    float* bnsums = (float*)alloc((size_t)NLAYERS * 2 * HID * 4);

    hipMemsetAsync(degi, 0, (size_t)N * 4, stream);
    hipMemsetAsync(fillc, 0, (size_t)N * 4, stream);
    hipMemsetAsync(bnsums, 0, (size_t)NLAYERS * 2 * HID * 4, stream);
    hipMemsetAsync(edges + E, 0, (size_t)EPAD * 8, stream);

    deg_kernel<<<(E + 255) / 256, 256, 0, stream>>>(dstp, degi, E);
    nrm_kernel<<<(N + 255) / 256, 256, 0, stream>>>(degi, nrm, N);
    scan_kernel<<<1, 1024, 0, stream>>>(degi, row_ptr, N);
    fill_kernel<<<(E + 255) / 256, 256, 0, stream>>>(srcp, dstp, row_ptr, fillc, nrm, edges, E);
    wcvt_kernel<<<dim3(8, 8, NLAYERS), 256, 0, stream>>>(W, wt);
    embed_kernel<<<N, 256, 0, stream>>>(x, emb, hbA, N);

    unsigned short* hbcur = hbA;
    unsigned short* hboth = hbB;
    int aggGrid = ((N + 7) / 8) * 2;
    for (int l = 0; l < NLAYERS; ++l) {
        float* lsums = bnsums + (size_t)l * 2 * HID;
        agg_pair_kernel<<<aggGrid, 256, 0, stream>>>(hbcur, row_ptr, edges, nrm, aggb, N);
        dim3 ggrid((N + 63) / 64, 4);
        mfma_gemm<<<ggrid, 256, 0, stream>>>(aggb, wt + (size_t)l * HID * HID,
                                             b + (size_t)l * HID, hwb, lsums, N);
        bn_kernel<<<((size_t)N * HID / 4 + 255) / 256, 256, 0, stream>>>(
            hwb, lsums, gamma + (size_t)l * HID, beta + (size_t)l * HID,
            hbcur, hboth, N);
        unsigned short* tb = hbcur; hbcur = hboth; hboth = tb;
    }

    pool_mlp_kernel<<<NGRAPHS, 256, 0, stream>>>(hbcur, batch, N, W1, b1, W2, b2, W3, b3, out);
}